// Round 2
// baseline (434.675 us; speedup 1.0000x reference)
//
#include <hip/hip_runtime.h>
#include <math.h>

#define B 8
#define C 512
#define K 19
#define HW 16384
#define ROWS (B * K)             // 152
#define L2E 1.44269504088896340736f

// gather config
#define NW 4                     // waves per block
#define CPW 4                    // c-rows per wave -> acc[4][19] = 76 VGPRs
#define CPB (CPW * NW)           // 16 c-rows per block
#define CG (C / CPB)             // 32 c-groups
#define NSC 4                    // grid = 8*32*4 = 1024 = 4 blocks/CU
#define SCHUNK (HW / NSC)        // 4096 s per block
#define TS 256                   // s-positions per tile (64 lanes x float4)
#define NT (SCHUNK / TS)         // 16 tiles per block

// Pass 1: full softmax per (b,k) row -> probs[] in workspace (10 MB).
// One block per row, 1024 threads, 16 elements/thread in registers.
// Blocks 0..18 additionally zero `out` (replaces the memset dispatch):
// 19 blocks x 1024 threads x 1 float4 = 311,296 B = exactly |out|.
__global__ __launch_bounds__(1024)
void probs_kernel(const float* __restrict__ aux, float* __restrict__ probs,
                  float* __restrict__ out) {
    int row  = blockIdx.x;                 // 0..151
    int tid  = threadIdx.x;                // 0..1023
    int lane = tid & 63;
    int wave = tid >> 6;
    __shared__ float red[16];

    if (row < 19)
        ((float4*)out)[(size_t)row * 1024 + tid] = make_float4(0.f, 0.f, 0.f, 0.f);

    const float4* x4 = (const float4*)(aux + (size_t)row * HW);
    float4*       p4 = (float4*)(probs + (size_t)row * HW);

    float4 v[4];
    #pragma unroll
    for (int i = 0; i < 4; i++) v[i] = x4[tid + i * 1024];

    float m = -INFINITY;
    #pragma unroll
    for (int i = 0; i < 4; i++)
        m = fmaxf(m, fmaxf(fmaxf(v[i].x, v[i].y), fmaxf(v[i].z, v[i].w)));
    #pragma unroll
    for (int off = 32; off > 0; off >>= 1) m = fmaxf(m, __shfl_xor(m, off, 64));
    if (lane == 0) red[wave] = m;
    __syncthreads();
    #pragma unroll
    for (int w = 0; w < 16; w++) m = fmaxf(m, red[w]);
    __syncthreads();                       // red[] reads done before reuse

    float nm = -m * L2E;
    float s = 0.f;
    #pragma unroll
    for (int i = 0; i < 4; i++) {
        v[i].x = exp2f(fmaf(v[i].x, L2E, nm));
        v[i].y = exp2f(fmaf(v[i].y, L2E, nm));
        v[i].z = exp2f(fmaf(v[i].z, L2E, nm));
        v[i].w = exp2f(fmaf(v[i].w, L2E, nm));
        s += (v[i].x + v[i].y) + (v[i].z + v[i].w);
    }
    #pragma unroll
    for (int off = 32; off > 0; off >>= 1) s += __shfl_xor(s, off, 64);
    if (lane == 0) red[wave] = s;
    __syncthreads();
    float Z = 0.f;
    #pragma unroll
    for (int w = 0; w < 16; w++) Z += red[w];
    float inv = 1.0f / Z;

    #pragma unroll
    for (int i = 0; i < 4; i++) {
        float4 o;
        o.x = v[i].x * inv; o.y = v[i].y * inv;
        o.z = v[i].z * inv; o.w = v[i].w * inv;
        p4[tid + i * 1024] = o;
    }
}

// Gather — barrier-free. ALLOCATOR LAW (R1-R5 measured): VGPR budget =
// 512/(2*declared_min_waves_per_eu). waves_per_eu(2) -> budget 128.
// Declaring 4 -> 64 VGPRs -> catastrophic spill. Do NOT "fix" this.
//
// vs previous version: NO LDS, NO __syncthreads. Each wave reads probs
// float4s directly from global; the per-tile probs working set (19 KiB per
// block, shared by 4 waves; one 304 KiB (b,sc) chunk shared by 32 blocks
// pinned to one XCD via the swizzle) lives in L1/L2, so the 4x read
// redundancy costs cache BW, not HBM. In exchange every wave is fully
// self-paced: the feats load pipeline is never drained to vmcnt(0) by a
// block-wide barrier, removing the per-tile burst/drain quantization.
// Occupancy: VGPR-bound at 4 waves/SIMD (16 waves/CU), same as before.
__global__ __launch_bounds__(256)
__attribute__((amdgpu_waves_per_eu(2)))
void gather_kernel(const float* __restrict__ feats, const float* __restrict__ probs,
                   float* __restrict__ out) {
    int bid = blockIdx.x;                  // 0..1023
    // consecutive bids round-robin XCDs; give each XCD 4 whole (b,sc) groups
    int xcd = bid & 7;
    int lid = xcd * 128 + (bid >> 3);
    int cg  = lid & (CG - 1);
    int grp = lid >> 5;                    // b*NSC + sc
    int sc  = grp & (NSC - 1);
    int b   = grp >> 2;

    int tid  = threadIdx.x;
    int lane = tid & 63;
    int wave = tid >> 6;
    int c0   = cg * CPB + wave * CPW;

    const float* Pbase = probs + (size_t)b * K * HW + sc * SCHUNK + lane * 4;
    const float* Fbase = feats + ((size_t)b * C + c0) * HW + sc * SCHUNK;

    float acc[CPW][K];
    #pragma unroll
    for (int c = 0; c < CPW; c++)
        #pragma unroll
        for (int k = 0; k < K; k++) acc[c][k] = 0.f;

    float4 f_cur[CPW], f_next[CPW];
    #pragma unroll
    for (int c = 0; c < CPW; c++)
        f_cur[c] = *(const float4*)(Fbase + c * HW + lane * 4);

    for (int t = 0; t < NT; t++) {
        int s = t * TS;
        // issue next feats tile first (HBM, longest latency distance)
        if (t + 1 < NT) {
            int s1 = s + TS;
            #pragma unroll
            for (int c = 0; c < CPW; c++)
                f_next[c] = *(const float4*)(Fbase + c * HW + s1 + lane * 4);
        }

        // probs straight from L1/L2, depth-2 software pipeline (bounded
        // register pressure: 2 float4 of p in flight, not 19).
        float4 p_cur = *(const float4*)(Pbase + s);
        #pragma unroll
        for (int k = 0; k < K; k++) {
            float4 p_nxt;
            if (k + 1 < K)
                p_nxt = *(const float4*)(Pbase + (size_t)(k + 1) * HW + s);
            #pragma unroll
            for (int c = 0; c < CPW; c++) {
                acc[c][k] = fmaf(p_cur.x, f_cur[c].x, acc[c][k]);
                acc[c][k] = fmaf(p_cur.y, f_cur[c].y, acc[c][k]);
                acc[c][k] = fmaf(p_cur.z, f_cur[c].z, acc[c][k]);
                acc[c][k] = fmaf(p_cur.w, f_cur[c].w, acc[c][k]);
            }
            p_cur = p_nxt;
        }

        #pragma unroll
        for (int c = 0; c < CPW; c++) f_cur[c] = f_next[c];
    }

    // butterfly reduce over 64 lanes, then one atomic per (c,k) per block
    #pragma unroll
    for (int c = 0; c < CPW; c++)
        #pragma unroll
        for (int k = 0; k < K; k++) {
            float v = acc[c][k];
            #pragma unroll
            for (int off = 32; off > 0; off >>= 1) v += __shfl_xor(v, off, 64);
            if (lane == 0)
                atomicAdd(&out[((size_t)b * C + c0 + c) * K + k], v);
        }
}

extern "C" void kernel_launch(void* const* d_in, const int* in_sizes, int n_in,
                              void* d_out, int out_size, void* d_ws, size_t ws_size,
                              hipStream_t stream) {
    const float* feats = (const float*)d_in[0];   // bb_feats [8,512,128,128]
    const float* aux   = (const float*)d_in[1];   // aux_out  [8,19,128,128]
    float* out   = (float*)d_out;                 // [8,512,19,1]
    float* probs = (float*)d_ws;                  // [8,19,16384] = 10 MB

    probs_kernel<<<ROWS, 1024, 0, stream>>>(aux, probs, out);
    gather_kernel<<<B * CG * NSC, 256, 0, stream>>>(feats, probs, out);
}

// Round 3
// 399.824 us; speedup vs baseline: 1.0872x; 1.0872x over previous
//
#include <hip/hip_runtime.h>
#include <math.h>

#define B 8
#define C 512
#define K 19
#define HW 16384
#define ROWS (B * K)             // 152
#define L2E 1.44269504088896340736f

// gather config
#define NW 4                     // waves per block
#define CPW 4                    // c-rows per wave -> acc[4][19] = 76 VGPRs
#define CPB (CPW * NW)           // 16 c-rows per block
#define CG (C / CPB)             // 32 c-groups
#define NSC 4                    // grid = 8*32*4 = 1024 = 4 blocks/CU
#define SCHUNK (HW / NSC)        // 4096 s per block
#define TS 256                   // s-tile staged in LDS
#define NT (SCHUNK / TS)         // 16 tiles per block

typedef __attribute__((address_space(3))) unsigned int lds_u32;
typedef const __attribute__((address_space(1))) unsigned int glb_u32;

// Pass 1: full softmax per (b,k) row -> probs[] (10 MB). Blocks 0..18 also
// zero `out` (19*1024*16 B = 311,296 B = |out|), replacing the memset.
__global__ __launch_bounds__(1024)
void probs_kernel(const float* __restrict__ aux, float* __restrict__ probs,
                  float* __restrict__ out) {
    int row  = blockIdx.x;                 // 0..151
    int tid  = threadIdx.x;                // 0..1023
    int lane = tid & 63;
    int wave = tid >> 6;
    __shared__ float red[16];

    if (row < 19)
        ((float4*)out)[(size_t)row * 1024 + tid] = make_float4(0.f, 0.f, 0.f, 0.f);

    const float4* x4 = (const float4*)(aux + (size_t)row * HW);
    float4*       p4 = (float4*)(probs + (size_t)row * HW);

    float4 v[4];
    #pragma unroll
    for (int i = 0; i < 4; i++) v[i] = x4[tid + i * 1024];

    float m = -INFINITY;
    #pragma unroll
    for (int i = 0; i < 4; i++)
        m = fmaxf(m, fmaxf(fmaxf(v[i].x, v[i].y), fmaxf(v[i].z, v[i].w)));
    #pragma unroll
    for (int off = 32; off > 0; off >>= 1) m = fmaxf(m, __shfl_xor(m, off, 64));
    if (lane == 0) red[wave] = m;
    __syncthreads();
    #pragma unroll
    for (int w = 0; w < 16; w++) m = fmaxf(m, red[w]);
    __syncthreads();

    float nm = -m * L2E;
    float s = 0.f;
    #pragma unroll
    for (int i = 0; i < 4; i++) {
        v[i].x = exp2f(fmaf(v[i].x, L2E, nm));
        v[i].y = exp2f(fmaf(v[i].y, L2E, nm));
        v[i].z = exp2f(fmaf(v[i].z, L2E, nm));
        v[i].w = exp2f(fmaf(v[i].w, L2E, nm));
        s += (v[i].x + v[i].y) + (v[i].z + v[i].w);
    }
    #pragma unroll
    for (int off = 32; off > 0; off >>= 1) s += __shfl_xor(s, off, 64);
    if (lane == 0) red[wave] = s;
    __syncthreads();
    float Z = 0.f;
    #pragma unroll
    for (int w = 0; w < 16; w++) Z += red[w];
    float inv = 1.0f / Z;

    #pragma unroll
    for (int i = 0; i < 4; i++) {
        float4 o;
        o.x = v[i].x * inv; o.y = v[i].y * inv;
        o.z = v[i].z * inv; o.w = v[i].w * inv;
        p4[tid + i * 1024] = o;
    }
}

// Gather — LDS-staged probs (R1 structure) but with counted-vmcnt raw
// barriers instead of __syncthreads (T4): the per-tile barrier drains ONLY
// the 5 probs global_load_lds (oldest in the vmcnt FIFO, vmcnt(4)); the 4
// feats loads stay in flight ACROSS the barrier with ~2-phase prefetch
// distance (static fA/fB ping-pong, explicit 2-tile unroll — rule #20).
// Per-block tile-order rotation de-phases the 4 co-resident blocks and
// spreads the chip-wide 64KB-strided feats bursts. Accumulation over s is
// order-independent, so any tile permutation is legal (probs+feats use the
// SAME rotated tile index).
//
// ALLOCATOR LAW (R1-R5 measured): VGPR budget = 512/(2*waves_per_eu(2)) = 128.
// Declaring 4 -> 64 VGPRs -> catastrophic spill. Do NOT "fix" this.
// Occupancy: LDS 38,912 B -> 4 blocks/CU = 16 waves/CU.
__global__ __launch_bounds__(256)
__attribute__((amdgpu_waves_per_eu(2)))
void gather_kernel(const float* __restrict__ feats, const float* __restrict__ probs,
                   float* __restrict__ out) {
    __shared__ float plds[2][K][TS];       // 38,912 B

    int bid = blockIdx.x;                  // 0..1023
    int xcd = bid & 7;
    int lid = xcd * 128 + (bid >> 3);      // XCD-contiguous remap
    int cg  = lid & (CG - 1);
    int grp = lid >> 5;                    // b*NSC + sc
    int sc  = grp & (NSC - 1);
    int b   = grp >> 2;
    int rot = (bid * 11) & (NT - 1);       // per-block tile-phase rotation

    int tid  = threadIdx.x;
    int lane = tid & 63;
    int wave = tid >> 6;
    int c0   = cg * CPB + wave * CPW;

    const float* Pbase = probs + (size_t)b * K * HW + sc * SCHUNK;
    const float* Fbase = feats + ((size_t)b * C + c0) * HW + sc * SCHUNK + lane * 4;

    float acc[CPW][K];
    #pragma unroll
    for (int c = 0; c < CPW; c++)
        #pragma unroll
        for (int k = 0; k < K; k++) acc[c][k] = 0.f;

    float4 fA[CPW], fB[CPW];

#define SROT(t) ((((t) + rot) & (NT - 1)) * TS)
#define STAGE(bi, t) do { int s_ = SROT(t); \
    for (int k = wave; k < K; k += NW) \
        __builtin_amdgcn_global_load_lds((glb_u32*)(Pbase + (size_t)k * HW + s_ + lane * 4), \
                                         (lds_u32*)&plds[bi][k][0], 16, 0, 0); } while (0)
#define FLOAD(fa, t) do { int s_ = SROT(t); \
    _Pragma("unroll") for (int c = 0; c < CPW; c++) \
        fa[c] = *(const float4*)(Fbase + (size_t)c * HW + s_); } while (0)
#define FMATILE(bi, fa) do { \
    _Pragma("unroll") for (int k = 0; k < K; k++) { \
        float4 pv = *(const float4*)(&plds[bi][k][lane * 4]); \
        _Pragma("unroll") for (int c = 0; c < CPW; c++) { \
            acc[c][k] = fmaf(pv.x, fa[c].x, acc[c][k]); \
            acc[c][k] = fmaf(pv.y, fa[c].y, acc[c][k]); \
            acc[c][k] = fmaf(pv.z, fa[c].z, acc[c][k]); \
            acc[c][k] = fmaf(pv.w, fa[c].w, acc[c][k]); } } } while (0)
// counted drain + raw barrier: retire the (oldest) staging loads, leave the
// newest `keep` feats loads in flight across the barrier.
#define WAITB(keep) do { \
    asm volatile("s_waitcnt vmcnt(" #keep ")" ::: "memory"); \
    __builtin_amdgcn_sched_barrier(0); \
    __builtin_amdgcn_s_barrier(); \
    __builtin_amdgcn_sched_barrier(0); } while (0)

    // prologue: probs(0)->buf0, feats(0)->fA, feats(1)->fB
    STAGE(0, 0);
    FLOAD(fA, 0);
    FLOAD(fB, 1);

    // steady state, 2-tile unrolled pairs: tiles 0..13
    #pragma unroll 1
    for (int tp = 0; tp < 7; ++tp) {
        int t = tp * 2;
        WAITB(4);                 // gll(t) done; feats(t+1) stays in flight
        STAGE(1, t + 1);
        FMATILE(0, fA);
        FLOAD(fA, t + 2);         // into just-consumed fA, used 2 tiles later
        WAITB(4);                 // gll(t+1) done; feats(t+2) in flight
        STAGE(0, t + 2);
        FMATILE(1, fB);
        FLOAD(fB, t + 3);
    }
    // tile 14
    WAITB(4);
    STAGE(1, 15);
    FMATILE(0, fA);
    // tile 15 (epilogue: full drain once)
    WAITB(0);
    FMATILE(1, fB);

#undef SROT
#undef STAGE
#undef FLOAD
#undef FMATILE
#undef WAITB

    // butterfly reduce over 64 lanes, then one atomic per (c,k) per block
    #pragma unroll
    for (int c = 0; c < CPW; c++)
        #pragma unroll
        for (int k = 0; k < K; k++) {
            float v = acc[c][k];
            #pragma unroll
            for (int off = 32; off > 0; off >>= 1) v += __shfl_xor(v, off, 64);
            if (lane == 0)
                atomicAdd(&out[((size_t)b * C + c0 + c) * K + k], v);
        }
}

extern "C" void kernel_launch(void* const* d_in, const int* in_sizes, int n_in,
                              void* d_out, int out_size, void* d_ws, size_t ws_size,
                              hipStream_t stream) {
    const float* feats = (const float*)d_in[0];   // bb_feats [8,512,128,128]
    const float* aux   = (const float*)d_in[1];   // aux_out  [8,19,128,128]
    float* out   = (float*)d_out;                 // [8,512,19,1]
    float* probs = (float*)d_ws;                  // [8,19,16384] = 10 MB

    probs_kernel<<<ROWS, 1024, 0, stream>>>(aux, probs, out);
    gather_kernel<<<B * CG * NSC, 256, 0, stream>>>(feats, probs, out);
}

// Round 4
// 397.270 us; speedup vs baseline: 1.0942x; 1.0064x over previous
//
#include <hip/hip_runtime.h>
#include <math.h>

#define B 8
#define C 512
#define K 19
#define HW 16384
#define ROWS (B * K)             // 152
#define L2E 1.44269504088896340736f

// gather config
#define NW 4                     // waves per block
#define CPW 4                    // c-rows per wave -> acc[4][19] = 76 VGPRs
#define CPB (CPW * NW)           // 16 c-rows per block
#define CG (C / CPB)             // 32 c-groups
#define NSC 4                    // grid = 8*32*4 = 1024 = 4 blocks/CU
#define SCHUNK (HW / NSC)        // 4096 s per block
#define TS 256                   // s-tile staged in LDS
#define NT (SCHUNK / TS)         // 16 tiles per block
#define TILE_F (K * TS)          // 4864 floats = 19,456 B per probs tile

typedef __attribute__((address_space(3))) unsigned int lds_u32;
typedef const __attribute__((address_space(1))) unsigned int glb_u32;

// Pass 1: row softmax -> probs in TILE-CONTIGUOUS layout:
//   probs[b][sc][t][k][TS]   (one gather tile = 19,456 B sequential)
// so gather's staging reads are sequential 1 KiB bursts instead of 5
// 64-KiB-strided streams per wave. Each wave here writes exactly one
// (t,k) row = 1 KiB contiguous per i-step (wave == tile index).
// Blocks 0..18 also zero `out` (19*1024*16 B = |out|), replacing memset.
__global__ __launch_bounds__(1024)
void probs_kernel(const float* __restrict__ aux, float* __restrict__ probs,
                  float* __restrict__ out) {
    int row  = blockIdx.x;                 // 0..151 = b*K + k
    int tid  = threadIdx.x;                // 0..1023
    int lane = tid & 63;
    int wave = tid >> 6;                   // == tile index t of this thread's s-range
    __shared__ float red[16];

    if (row < 19)
        ((float4*)out)[(size_t)row * 1024 + tid] = make_float4(0.f, 0.f, 0.f, 0.f);

    const float4* x4 = (const float4*)(aux + (size_t)row * HW);

    float4 v[4];
    #pragma unroll
    for (int i = 0; i < 4; i++) v[i] = x4[tid + i * 1024];   // i == sc

    float m = -INFINITY;
    #pragma unroll
    for (int i = 0; i < 4; i++)
        m = fmaxf(m, fmaxf(fmaxf(v[i].x, v[i].y), fmaxf(v[i].z, v[i].w)));
    #pragma unroll
    for (int off = 32; off > 0; off >>= 1) m = fmaxf(m, __shfl_xor(m, off, 64));
    if (lane == 0) red[wave] = m;
    __syncthreads();
    #pragma unroll
    for (int w = 0; w < 16; w++) m = fmaxf(m, red[w]);
    __syncthreads();

    float nm = -m * L2E;
    float s = 0.f;
    #pragma unroll
    for (int i = 0; i < 4; i++) {
        v[i].x = exp2f(fmaf(v[i].x, L2E, nm));
        v[i].y = exp2f(fmaf(v[i].y, L2E, nm));
        v[i].z = exp2f(fmaf(v[i].z, L2E, nm));
        v[i].w = exp2f(fmaf(v[i].w, L2E, nm));
        s += (v[i].x + v[i].y) + (v[i].z + v[i].w);
    }
    #pragma unroll
    for (int off = 32; off > 0; off >>= 1) s += __shfl_xor(s, off, 64);
    if (lane == 0) red[wave] = s;
    __syncthreads();
    float Z = 0.f;
    #pragma unroll
    for (int w = 0; w < 16; w++) Z += red[w];
    float inv = 1.0f / Z;

    int b = row / K, k = row - b * K;
    float4* dst4 = (float4*)probs;
    #pragma unroll
    for (int i = 0; i < 4; i++) {
        float4 o;
        o.x = v[i].x * inv; o.y = v[i].y * inv;
        o.z = v[i].z * inv; o.w = v[i].w * inv;
        // s0 = 4*tid + i*SCHUNK -> sc=i, t=wave, ts=lane*4
        size_t idx = ((((size_t)(b * NSC + i) * NT + wave) * K + k) << 6) + lane;
        dst4[idx] = o;
    }
}

// Gather — LDS-staged probs from the tile-contiguous workspace layout.
// Per tile the block stages one 19,456 B SEQUENTIAL chunk via 19 full-wave
// global_load_lds dwordx4 (5/5/5/4 per wave), instead of 20 scattered
// 64-KiB-strided 1 KiB requests. Counted-vmcnt raw barriers (T4) keep the
// 4 feats loads in flight across the barrier; sched_barrier after STAGE
// pins gll-before-feats issue order so WAITB(4) retires exactly
// {prev feats, gll(t)} and keeps exactly the 4 newest feats loads.
// s_setprio(1) wraps the FMA cluster (T5: 4 independently-phased blocks
// per SIMD -> scheduler has roles to arbitrate).
//
// ALLOCATOR LAW (R1-R5 measured): VGPR budget = 512/(2*waves_per_eu(2)) = 128.
// Declaring 4 -> 64 VGPRs -> catastrophic spill. Do NOT "fix" this.
// Occupancy: LDS 38,912 B -> 4 blocks/CU = 16 waves/CU.
__global__ __launch_bounds__(256)
__attribute__((amdgpu_waves_per_eu(2)))
void gather_kernel(const float* __restrict__ feats, const float* __restrict__ probs,
                   float* __restrict__ out) {
    __shared__ __align__(16) float plds[2][K][TS];   // 38,912 B

    int bid = blockIdx.x;                  // 0..1023
    int xcd = bid & 7;
    int lid = xcd * 128 + (bid >> 3);      // XCD-contiguous remap
    int cg  = lid & (CG - 1);
    int grp = lid >> 5;                    // b*NSC + sc
    int sc  = grp & (NSC - 1);
    int b   = grp >> 2;
    int rot = (bid * 11) & (NT - 1);       // per-block tile-phase rotation

    int tid  = threadIdx.x;
    int lane = tid & 63;
    int wave = tid >> 6;
    int c0   = cg * CPB + wave * CPW;

    const float* Pbase = probs + (size_t)(b * NSC + sc) * (NT * TILE_F);
    const float* Fbase = feats + ((size_t)b * C + c0) * HW + sc * SCHUNK + lane * 4;

    float acc[CPW][K];
    #pragma unroll
    for (int c = 0; c < CPW; c++)
        #pragma unroll
        for (int k = 0; k < K; k++) acc[c][k] = 0.f;

    float4 fA[CPW], fB[CPW];

#define SROT(t) (((t) + rot) & (NT - 1))
#define STAGE(bi, t) do { \
    const float* pt_ = Pbase + (size_t)SROT(t) * TILE_F; \
    for (int i = wave; i < K; i += NW) \
        __builtin_amdgcn_global_load_lds((glb_u32*)(pt_ + i * TS + lane * 4), \
                                         (lds_u32*)(&plds[bi][0][0] + i * TS), 16, 0, 0); \
    __builtin_amdgcn_sched_barrier(0); } while (0)
#define FLOAD(fa, t) do { int s_ = SROT(t) * TS; \
    _Pragma("unroll") for (int c = 0; c < CPW; c++) \
        fa[c] = *(const float4*)(Fbase + (size_t)c * HW + s_); } while (0)
#define FMATILE(bi, fa) do { \
    __builtin_amdgcn_s_setprio(1); \
    _Pragma("unroll") for (int k = 0; k < K; k++) { \
        float4 pv = *(const float4*)(&plds[bi][k][lane * 4]); \
        _Pragma("unroll") for (int c = 0; c < CPW; c++) { \
            acc[c][k] = fmaf(pv.x, fa[c].x, acc[c][k]); \
            acc[c][k] = fmaf(pv.y, fa[c].y, acc[c][k]); \
            acc[c][k] = fmaf(pv.z, fa[c].z, acc[c][k]); \
            acc[c][k] = fmaf(pv.w, fa[c].w, acc[c][k]); } } \
    __builtin_amdgcn_s_setprio(0); } while (0)
#define WAITB(keep) do { \
    asm volatile("s_waitcnt vmcnt(" #keep ")" ::: "memory"); \
    __builtin_amdgcn_sched_barrier(0); \
    __builtin_amdgcn_s_barrier(); \
    __builtin_amdgcn_sched_barrier(0); } while (0)

    // prologue: probs(0)->buf0, feats(0)->fA, feats(1)->fB
    STAGE(0, 0);
    FLOAD(fA, 0);
    FLOAD(fB, 1);

    // steady state, 2-tile unrolled pairs: tiles 0..13
    #pragma unroll 1
    for (int tp = 0; tp < 7; ++tp) {
        int t = tp * 2;
        WAITB(4);                 // gll(t)+old feats done; 4 newest feats in flight
        STAGE(1, t + 1);
        FMATILE(0, fA);
        FLOAD(fA, t + 2);         // used 2 tiles later
        WAITB(4);
        STAGE(0, t + 2);
        FMATILE(1, fB);
        FLOAD(fB, t + 3);
    }
    // tile 14
    WAITB(4);
    STAGE(1, 15);
    FMATILE(0, fA);
    // tile 15 (epilogue: full drain once)
    WAITB(0);
    FMATILE(1, fB);

#undef SROT
#undef STAGE
#undef FLOAD
#undef FMATILE
#undef WAITB

    // butterfly reduce over 64 lanes, then one atomic per (c,k) per block
    #pragma unroll
    for (int c = 0; c < CPW; c++)
        #pragma unroll
        for (int k = 0; k < K; k++) {
            float v = acc[c][k];
            #pragma unroll
            for (int off = 32; off > 0; off >>= 1) v += __shfl_xor(v, off, 64);
            if (lane == 0)
                atomicAdd(&out[((size_t)b * C + c0 + c) * K + k], v);
        }
}

extern "C" void kernel_launch(void* const* d_in, const int* in_sizes, int n_in,
                              void* d_out, int out_size, void* d_ws, size_t ws_size,
                              hipStream_t stream) {
    const float* feats = (const float*)d_in[0];   // bb_feats [8,512,128,128]
    const float* aux   = (const float*)d_in[1];   // aux_out  [8,19,128,128]
    float* out   = (float*)d_out;                 // [8,512,19,1]
    float* probs = (float*)d_ws;                  // tiled [8][4][16][19][256] = 10 MB

    probs_kernel<<<ROWS, 1024, 0, stream>>>(aux, probs, out);
    gather_kernel<<<B * CG * NSC, 256, 0, stream>>>(feats, probs, out);
}